// Round 18
// baseline (152.188 us; speedup 1.0000x reference)
//
#include <hip/hip_runtime.h>

typedef unsigned short u16;
typedef unsigned int u32;
typedef __attribute__((ext_vector_type(4))) float f32x4;
typedef __attribute__((ext_vector_type(8))) short bf16x8;
typedef __attribute__((ext_vector_type(4))) unsigned short u16x4;

#define MFMA(a, b, c) __builtin_amdgcn_mfma_f32_16x16x32_bf16((a), (b), (c), 0, 0, 0)

static constexpr int M_TOK = 8192;  // B*S

__device__ __forceinline__ u16 f2bf(float f) {
  u32 u = __float_as_uint(f);
  return (u16)((u + 0x7FFFu + ((u >> 16) & 1u)) >> 16);  // RNE
}
__device__ __forceinline__ float bf2f(u16 b) {
  u32 u = ((u32)b) << 16;
  return __uint_as_float(u);
}
__device__ __forceinline__ void gload16(const u16* g, u16* l) {
  __builtin_amdgcn_global_load_lds(
      (const __attribute__((address_space(1))) u32*)(const void*)g,
      (__attribute__((address_space(3))) u32*)(void*)l, 16, 0, 0);
}

#define PH_BAR()                                       \
  do {                                                 \
    __builtin_amdgcn_s_barrier();                      \
    asm volatile("s_waitcnt lgkmcnt(0)" ::: "memory"); \
  } while (0)
#define PH_END() __builtin_amdgcn_s_barrier()

// ---- elementwise fp32 -> bf16 cast ----
__global__ void cast_x_kernel(const float* __restrict__ in, u16* __restrict__ out, int total4) {
  for (int i = blockIdx.x * blockDim.x + threadIdx.x; i < total4; i += gridDim.x * blockDim.x) {
    float4 v = ((const float4*)in)[i];
    u16x4 o;
    o[0] = f2bf(v.x); o[1] = f2bf(v.y); o[2] = f2bf(v.z); o[3] = f2bf(v.w);
    ((u16x4*)out)[i] = o;
  }
}

// ---- transpose + cast: in [z][P][Q] fp32 -> out [z][Q][P] bf16 ----
__global__ void tcast_kernel(const float* __restrict__ in, u16* __restrict__ out, int P, int Q) {
  __shared__ float tile[32][33];
  const int z = blockIdx.z;
  const int q0 = blockIdx.x * 32, p0 = blockIdx.y * 32;
  const float* src = in + (size_t)z * P * Q;
  u16* dst = out + (size_t)z * P * Q;
  const int tx = threadIdx.x & 31, ty = threadIdx.x >> 5;
#pragma unroll
  for (int k = 0; k < 4; ++k)
    tile[ty + k * 8][tx] = src[(size_t)(p0 + ty + k * 8) * Q + q0 + tx];
  __syncthreads();
#pragma unroll
  for (int k = 0; k < 4; ++k)
    dst[(size_t)(q0 + ty + k * 8) * P + p0 + tx] = f2bf(tile[tx][ty + k * 8]);
}

// ================= GEMM1+combine fused (R17 best): h = sum_n wf_n*(x@F_n) =================
__global__ __launch_bounds__(512, 2) void gemm_h(
    const u16* __restrict__ A, const u16* __restrict__ Bm,
    const float* __restrict__ Wf, u16* __restrict__ Hout, const int K) {
  constexpr int NITER = 8;
  __shared__ u16 lds[65536];
  __shared__ float wf_lds[256 * 16];

  const int tid = threadIdx.x;
  const int lane = tid & 63;
  const int wid = tid >> 6;
  const int wr = wid >> 2, wc = wid & 3;

  const int L = blockIdx.y * gridDim.x + blockIdx.x;
  const int ordered = (L & 7) * 64 + (L >> 3);
  const int cid = ordered >> 5, win = ordered & 31;
  const int bx = (cid & 3) * 4 + (win & 3);
  const int by = (cid >> 2) * 8 + (win >> 2);
  const int m0 = by * 256, bx16 = bx * 16;

  const int arow = lane & 15;
  const int acol = (lane >> 4) * 16;
  const int sw = (arow & 7) << 4;
  const int lo0 = arow * 128 + (acol ^ sw);
  const int lo1 = arow * 128 + ((64 + acol) ^ sw);

  const u16* Abase = A + (size_t)m0 * K;

#pragma unroll
  for (int t = 0; t < 2; ++t) {
    const int i4 = t * 512 + tid;
    *(float4*)&wf_lds[i4 * 4] = *(const float4*)&Wf[(size_t)m0 * 16 + i4 * 4];
  }

  f32x4 acc[8][4];
#pragma unroll
  for (int i = 0; i < 8; ++i)
#pragma unroll
    for (int j = 0; j < 4; ++j) acc[i][j] = (f32x4){0.f, 0.f, 0.f, 0.f};

  auto STAGE = [&](int b, int isB, int hf, int kt) {
    u16* Lp = &lds[isB * 32768 + (b * 2 + hf) * 8192];
#pragma unroll
    for (int j = 0; j < 2; ++j) {
      const int q = j * 8192 + tid * 16;
      const int tr = hf * 128 + (q >> 7);
      const int gcol = ((q & 127) ^ (((q >> 7) & 7) << 4)) >> 1;
      const u16* gp = isB
          ? Bm + (size_t)((tr >> 4) * 256 + bx16 + (tr & 15)) * K + kt * 64 + gcol
          : Abase + (size_t)tr * K + kt * 64 + gcol;
      gload16(gp, Lp + ((j * 8192 + wid * 1024) >> 1));
    }
  };
  auto LOAD_AV = [&](bf16x8 (&v)[4][2], int b, int mh) {
    const char* p = (const char*)lds + b * 32768 + (wr * 128 + mh * 64) * 128;
#pragma unroll
    for (int mi = 0; mi < 4; ++mi) {
      v[mi][0] = *(const bf16x8*)(p + mi * 2048 + lo0);
      v[mi][1] = *(const bf16x8*)(p + mi * 2048 + lo1);
    }
  };
  auto LOAD_BV = [&](bf16x8 (&v)[2][2], int b, int nq) {
#pragma unroll
    for (int nj = 0; nj < 2; ++nj) {
      const int rb = wc * 64 + (nq * 2 + nj) * 16;
      const char* p = (const char*)lds + 65536 + b * 32768 + rb * 128;
      v[nj][0] = *(const bf16x8*)(p + lo0);
      v[nj][1] = *(const bf16x8*)(p + lo1);
    }
  };

#define QUAD2(AV, BV0, BV1, MH)                                                \
  do {                                                                         \
    _Pragma("unroll") for (int ks = 0; ks < 2; ++ks) {                         \
      _Pragma("unroll") for (int mi = 0; mi < 4; ++mi) {                       \
        _Pragma("unroll") for (int nj = 0; nj < 2; ++nj) {                     \
          acc[(MH)*4 + mi][nj] = MFMA(AV[mi][ks], BV0[nj][ks], acc[(MH)*4 + mi][nj]); \
          acc[(MH)*4 + mi][2 + nj] = MFMA(AV[mi][ks], BV1[nj][ks], acc[(MH)*4 + mi][2 + nj]); \
        }                                                                      \
      }                                                                        \
    }                                                                          \
  } while (0)

  bf16x8 av[4][2], avh[4][2], bv0[2][2], bv1[2][2];

  STAGE(0, 0, 0, 0); STAGE(0, 0, 1, 0); STAGE(0, 1, 0, 0); STAGE(0, 1, 1, 0);
  STAGE(1, 1, 0, 1); STAGE(1, 0, 0, 1);
  asm volatile("s_waitcnt vmcnt(4)" ::: "memory");
  __builtin_amdgcn_s_barrier();

#pragma unroll 1
  for (int i = 0; i < NITER; ++i) {
    const int ta = 2 * i, tb = ta + 1;
    const bool st = (i + 1 < NITER);
    LOAD_AV(av, 0, 0); LOAD_BV(bv0, 0, 0); LOAD_BV(bv1, 0, 1);
    STAGE(1, 0, 1, tb); STAGE(1, 1, 1, tb);
    PH_BAR();
    QUAD2(av, bv0, bv1, 0);
    PH_END();
    LOAD_AV(avh, 0, 1);
    if (st) { STAGE(0, 1, 0, ta + 2); STAGE(0, 0, 0, ta + 2); }
    PH_BAR();
    QUAD2(avh, bv0, bv1, 1);
    if (st) asm volatile("s_waitcnt vmcnt(4)" ::: "memory");
    else    asm volatile("s_waitcnt vmcnt(0)" ::: "memory");
    PH_END();
    LOAD_AV(av, 1, 0); LOAD_BV(bv0, 1, 0); LOAD_BV(bv1, 1, 1);
    if (st) { STAGE(0, 0, 1, ta + 2); STAGE(0, 1, 1, ta + 2); }
    PH_BAR();
    QUAD2(av, bv0, bv1, 0);
    PH_END();
    LOAD_AV(avh, 1, 1);
    if (st) { STAGE(1, 1, 0, tb + 2); STAGE(1, 0, 0, tb + 2); }
    PH_BAR();
    QUAD2(avh, bv0, bv1, 1);
    if (st) asm volatile("s_waitcnt vmcnt(4)" ::: "memory");
    PH_END();
  }

  __syncthreads();
  float* pbuf = (float*)lds;
#pragma unroll
  for (int MI = 0; MI < 8; ++MI) {
    const int mbase = wr * 128 + MI * 16 + (lane >> 4) * 4;
#pragma unroll
    for (int j = 0; j < 4; ++j) {
      const float4 wf4 = *(const float4*)&wf_lds[(mbase + j) * 16 + wc * 4];
      const float p = wf4.x * acc[MI][0][j] + wf4.y * acc[MI][1][j] +
                      wf4.z * acc[MI][2][j] + wf4.w * acc[MI][3][j];
      pbuf[wc * 4096 + (mbase + j) * 16 + (lane & 15)] = p;
    }
  }
  __syncthreads();
  {
    const int m = tid >> 1, r8 = (tid & 1) * 8;
    float s[8];
#pragma unroll
    for (int r = 0; r < 8; ++r) s[r] = 0.f;
#pragma unroll
    for (int w = 0; w < 4; ++w) {
      const float4 a = *(const float4*)&pbuf[w * 4096 + m * 16 + r8];
      const float4 b = *(const float4*)&pbuf[w * 4096 + m * 16 + r8 + 4];
      s[0] += a.x; s[1] += a.y; s[2] += a.z; s[3] += a.w;
      s[4] += b.x; s[5] += b.y; s[6] += b.z; s[7] += b.w;
    }
    bf16x8 o;
#pragma unroll
    for (int r = 0; r < 8; ++r) o[r] = (short)f2bf(s[r]);
    *(bf16x8*)&Hout[(size_t)(m0 + m) * 256 + bx16 + r8] = o;
  }
}
#undef QUAD2

// ============ GEMM2: MERGED phase — one barrier section per expert group ============
// Group-parity double buffer: group g lives in ldsB[4(g&1) .. 4(g&1)+3].
// Phase g: read bv(h0) | stage ENTIRE group g+1 (8 gloads) | BAR+lgkm |
// 32 MFMA h0 (C=vz) | reload bv in-place for h1 (hides under h0 MFMAs) |
// 32 MFMA h1 | vmcnt(0) | BAR | FOLD(g).  16 phases instead of 32.
__global__ __launch_bounds__(512, 2) void gemm_fold(
    const u16* __restrict__ A,    // h  [8192][256] bf16
    const u16* __restrict__ Bn,   // Rt [16][1024][256] bf16
    const float* __restrict__ W,  // Wr [8192][16] f32
    float* __restrict__ Out) {    // [8192][1024] f32
  __shared__ u16 ldsB[8][8192];   // 128 KB: 2 group-buffers of 4 half-tiles
  __shared__ float Wlds[16][132]; // f32 weights, [n][row]

  const int tid = threadIdx.x;
  const int lane = tid & 63;
  const int wid = tid >> 6;
  const int kh = wid >> 2;
  const int wrM = (wid >> 1) & 1;
  const int wcN = wid & 1;

  // L2-aware chunked XCD swizzle: chunk = 2 bx x 16 by
  const int L = blockIdx.y * gridDim.x + blockIdx.x;
  const int ordered = (L & 7) * 64 + (L >> 3);
  const int cid = ordered >> 5, win = ordered & 31;
  const int bx = (cid & 3) * 2 + (win & 1);
  const int by = (cid >> 2) * 16 + (win >> 1);
  const int m0 = by * 128, d0 = bx * 128;

  const int arow = lane & 15;
  const int acol = (lane >> 4) * 16;
  const int sw = (arow & 7) << 4;
  const int lo0 = arow * 128 + (acol ^ sw);
  const int lo1 = arow * 128 + ((64 + acol) ^ sw);

  for (int i = tid; i < 128 * 16; i += 512) {
    const int row = i >> 4, n = i & 15;
    Wlds[n][row] = W[(size_t)(m0 + row) * 16 + n];
  }

  auto ASTAGE = [&](int kt) {
    const u16* G = A + (size_t)m0 * 256;
    u16* Lp = &ldsB[kt][0];
#pragma unroll
    for (int j = 0; j < 2; ++j) {
      const int q = j * 8192 + tid * 16;
      const int grow = q >> 7;
      const int gcol = ((q & 127) ^ (((q >> 7) & 7) << 4)) >> 1;
      gload16(G + (size_t)grow * 256 + kt * 64 + gcol, Lp + ((j * 8192 + wid * 1024) >> 1));
    }
  };
  ASTAGE(0); ASTAGE(1); ASTAGE(2); ASTAGE(3);
  __syncthreads();
  bf16x8 avk[4][4];
#pragma unroll
  for (int c2 = 0; c2 < 2; ++c2) {
#pragma unroll
    for (int mi = 0; mi < 4; ++mi) {
      const char* p = (const char*)&ldsB[kh * 2 + c2][0] + (wrM * 64 + mi * 16) * 128;
      avk[c2 * 2 + 0][mi] = *(const bf16x8*)(p + lo0);
      avk[c2 * 2 + 1][mi] = *(const bf16x8*)(p + lo1);
    }
  }
  __syncthreads();

  // stage ENTIRE group g (4 half-tiles, 8 gloads/thread) into buffer-half g&1
  auto BSTAGE_G = [&](int g) {
    const u16* G = Bn + ((size_t)g * 1024 + d0) * 256;
    const int base = 4 * (g & 1);
#pragma unroll
    for (int h = 0; h < 2; ++h) {
#pragma unroll
      for (int t = 0; t < 2; ++t) {
        u16* Lp = &ldsB[base + 2 * h + t][0];
        const int kt = h + 2 * t;
#pragma unroll
        for (int j = 0; j < 2; ++j) {
          const int q = j * 8192 + tid * 16;
          const int grow = q >> 7;
          const int gcol = ((q & 127) ^ (((q >> 7) & 7) << 4)) >> 1;
          gload16(G + (size_t)grow * 256 + kt * 64 + gcol, Lp + ((j * 8192 + wid * 1024) >> 1));
        }
      }
    }
  };

  f32x4 acc_t[4][4], acc_g[4][4];
#pragma unroll
  for (int mi = 0; mi < 4; ++mi)
#pragma unroll
    for (int nj = 0; nj < 4; ++nj) {
      acc_t[mi][nj] = (f32x4){0.f, 0.f, 0.f, 0.f};
      acc_g[mi][nj] = (f32x4){0.f, 0.f, 0.f, 0.f};
    }
  const f32x4 vz = {0.f, 0.f, 0.f, 0.f};
  bf16x8 bv[4][2];
  const int wrow = wrM * 64 + (lane >> 4) * 4;  // + mi*16 per fragment

  BSTAGE_G(0);
  asm volatile("s_waitcnt vmcnt(0)" ::: "memory");
  __builtin_amdgcn_s_barrier();

  auto BVLOAD = [&](int buf) {
    const char* pB = (const char*)&ldsB[buf][0];
#pragma unroll
    for (int nj = 0; nj < 4; ++nj) {
      const char* q = pB + (wcN * 64 + nj * 16) * 128;
      bv[nj][0] = *(const bf16x8*)(q + lo0);
      bv[nj][1] = *(const bf16x8*)(q + lo1);
    }
  };
  // slim FOLD: 4 LDS float4 reads + 16 vector fma
  auto FOLD = [&](int n) {
#pragma unroll
    for (int mi = 0; mi < 4; ++mi) {
      const float4 w = *(const float4*)&Wlds[n][wrow + mi * 16];
      const f32x4 wv = {w.x, w.y, w.z, w.w};
#pragma unroll
      for (int nj = 0; nj < 4; ++nj)
        acc_t[mi][nj] += wv * acc_g[mi][nj];
    }
  };

#pragma unroll 1
  for (int g = 0; g < 16; ++g) {
    const int base = 4 * (g & 1);
    const bool st = (g < 15);
    // pre-barrier: bv for h=0 slice (kh), and stage next group
    BVLOAD(base + kh);
    if (st) BSTAGE_G(g + 1);
    PH_BAR();
    // h0: 32 MFMA, group start -> C = vz
#pragma unroll
    for (int mi = 0; mi < 4; ++mi)
#pragma unroll
      for (int nj = 0; nj < 4; ++nj)
        acc_g[mi][nj] = MFMA(avk[0][mi], bv[nj][0], vz);
#pragma unroll
    for (int mi = 0; mi < 4; ++mi)
#pragma unroll
      for (int nj = 0; nj < 4; ++nj)
        acc_g[mi][nj] = MFMA(avk[1][mi], bv[nj][1], acc_g[mi][nj]);
    // reload bv in place for h=1 (same group, staged pre-phase; reads hide
    // under the h0 MFMA cluster via compiler-counted lgkm waits)
    BVLOAD(base + 2 + kh);
#pragma unroll
    for (int mi = 0; mi < 4; ++mi)
#pragma unroll
      for (int nj = 0; nj < 4; ++nj)
        acc_g[mi][nj] = MFMA(avk[2][mi], bv[nj][0], acc_g[mi][nj]);
#pragma unroll
    for (int mi = 0; mi < 4; ++mi)
#pragma unroll
      for (int nj = 0; nj < 4; ++nj)
        acc_g[mi][nj] = MFMA(avk[3][mi], bv[nj][1], acc_g[mi][nj]);
    if (st) asm volatile("s_waitcnt vmcnt(0)" ::: "memory");
    PH_END();
    FOLD(g);
  }

  // ---- epilogue: kh-reduce via LDS f32 regions, direct store ----
  __syncthreads();
  float* red = (float*)&ldsB[0][0];
  const int reg = (wrM * 2 + wcN) * 4096;
  if (kh == 1) {
#pragma unroll
    for (int mi = 0; mi < 4; ++mi)
#pragma unroll
      for (int j = 0; j < 4; ++j) {
        const int r = mi * 16 + (lane >> 4) * 4 + j;
#pragma unroll
        for (int nj = 0; nj < 4; ++nj)
          red[reg + r * 64 + nj * 16 + (lane & 15)] = acc_t[mi][nj][j];
      }
  }
  __syncthreads();
  if (kh == 0) {
#pragma unroll
    for (int mi = 0; mi < 4; ++mi) {
      const int rr = mi * 16 + (lane >> 4) * 4;
#pragma unroll
      for (int j = 0; j < 4; ++j) {
        float* orow = Out + (size_t)(m0 + wrM * 64 + rr + j) * 1024 + d0 + wcN * 64 + (lane & 15);
#pragma unroll
        for (int nj = 0; nj < 4; ++nj)
          orow[nj * 16] = acc_t[mi][nj][j] + red[reg + (rr + j) * 64 + nj * 16 + (lane & 15)];
      }
    }
  }
}

extern "C" void kernel_launch(void* const* d_in, const int* in_sizes, int n_in,
                              void* d_out, int out_size, void* d_ws, size_t ws_size,
                              hipStream_t stream) {
  const float* x  = (const float*)d_in[0];   // [8192][1024]
  const float* F  = (const float*)d_in[1];   // [16][1024][256]
  const float* Rk = (const float*)d_in[2];   // [16][256][1024]
  const float* Wf = (const float*)d_in[3];   // [8192][16]
  const float* Wr = (const float*)d_in[4];   // [8192][16]
  float* out = (float*)d_out;                // [8192][1024]

  char* ws = (char*)d_ws;
  u16* X16 = (u16*)(ws);                 // 16 MB  x bf16 [8192][1024]
  u16* B1  = (u16*)(ws + (16u << 20));   //  8 MB  F^T  [(n,r)=4096][1024]
  u16* Rt  = (u16*)(ws + (24u << 20));   //  8 MB  Rk^T [16][1024][256]
  u16* h16 = (u16*)(ws + (32u << 20));   //  4 MB  h bf16 [8192][256]

  cast_x_kernel<<<2048, 256, 0, stream>>>(x, X16, (M_TOK * 1024) / 4);
  tcast_kernel<<<dim3(8, 32, 16), 256, 0, stream>>>(F, B1, 1024, 256);
  tcast_kernel<<<dim3(32, 8, 16), 256, 0, stream>>>(Rk, Rt, 256, 1024);

  // fused stage 1: h = sum_n wf_n * (x @ F_n)
  gemm_h<<<dim3(16, 32, 1), 512, 0, stream>>>(X16, B1, Wf, h16, 1024);

  // stage 2: out = sum_n wr_n * (h @ Rt[n]), merged 16-phase schedule
  gemm_fold<<<dim3(8, 64, 1), 512, 0, stream>>>(h16, Rt, Wr, out);
}

// Round 19
// 144.475 us; speedup vs baseline: 1.0534x; 1.0534x over previous
//
#include <hip/hip_runtime.h>

typedef unsigned short u16;
typedef unsigned int u32;
typedef __attribute__((ext_vector_type(4))) float f32x4;
typedef __attribute__((ext_vector_type(8))) short bf16x8;
typedef __attribute__((ext_vector_type(4))) unsigned short u16x4;

#define MFMA(a, b, c) __builtin_amdgcn_mfma_f32_16x16x32_bf16((a), (b), (c), 0, 0, 0)

static constexpr int M_TOK = 8192;  // B*S

__device__ __forceinline__ u16 f2bf(float f) {
  u32 u = __float_as_uint(f);
  return (u16)((u + 0x7FFFu + ((u >> 16) & 1u)) >> 16);  // RNE
}
__device__ __forceinline__ float bf2f(u16 b) {
  u32 u = ((u32)b) << 16;
  return __uint_as_float(u);
}
__device__ __forceinline__ void gload16(const u16* g, u16* l) {
  __builtin_amdgcn_global_load_lds(
      (const __attribute__((address_space(1))) u32*)(const void*)g,
      (__attribute__((address_space(3))) u32*)(void*)l, 16, 0, 0);
}

#define PH_BAR()                                       \
  do {                                                 \
    __builtin_amdgcn_s_barrier();                      \
    asm volatile("s_waitcnt lgkmcnt(0)" ::: "memory"); \
  } while (0)
#define PH_END() __builtin_amdgcn_s_barrier()

// ---- elementwise fp32 -> bf16 cast ----
__global__ void cast_x_kernel(const float* __restrict__ in, u16* __restrict__ out, int total4) {
  for (int i = blockIdx.x * blockDim.x + threadIdx.x; i < total4; i += gridDim.x * blockDim.x) {
    float4 v = ((const float4*)in)[i];
    u16x4 o;
    o[0] = f2bf(v.x); o[1] = f2bf(v.y); o[2] = f2bf(v.z); o[3] = f2bf(v.w);
    ((u16x4*)out)[i] = o;
  }
}

// ---- transpose + cast: in [z][P][Q] fp32 -> out [z][Q][P] bf16 ----
__global__ void tcast_kernel(const float* __restrict__ in, u16* __restrict__ out, int P, int Q) {
  __shared__ float tile[32][33];
  const int z = blockIdx.z;
  const int q0 = blockIdx.x * 32, p0 = blockIdx.y * 32;
  const float* src = in + (size_t)z * P * Q;
  u16* dst = out + (size_t)z * P * Q;
  const int tx = threadIdx.x & 31, ty = threadIdx.x >> 5;
#pragma unroll
  for (int k = 0; k < 4; ++k)
    tile[ty + k * 8][tx] = src[(size_t)(p0 + ty + k * 8) * Q + q0 + tx];
  __syncthreads();
#pragma unroll
  for (int k = 0; k < 4; ++k)
    dst[(size_t)(q0 + ty + k * 8) * P + p0 + tx] = f2bf(tile[tx][ty + k * 8]);
}

// ================= GEMM1+combine fused (R17 best): h = sum_n wf_n*(x@F_n) =================
__global__ __launch_bounds__(512, 2) void gemm_h(
    const u16* __restrict__ A, const u16* __restrict__ Bm,
    const float* __restrict__ Wf, u16* __restrict__ Hout, const int K) {
  constexpr int NITER = 8;
  __shared__ u16 lds[65536];
  __shared__ float wf_lds[256 * 16];

  const int tid = threadIdx.x;
  const int lane = tid & 63;
  const int wid = tid >> 6;
  const int wr = wid >> 2, wc = wid & 3;

  const int L = blockIdx.y * gridDim.x + blockIdx.x;
  const int ordered = (L & 7) * 64 + (L >> 3);
  const int cid = ordered >> 5, win = ordered & 31;
  const int bx = (cid & 3) * 4 + (win & 3);
  const int by = (cid >> 2) * 8 + (win >> 2);
  const int m0 = by * 256, bx16 = bx * 16;

  const int arow = lane & 15;
  const int acol = (lane >> 4) * 16;
  const int sw = (arow & 7) << 4;
  const int lo0 = arow * 128 + (acol ^ sw);
  const int lo1 = arow * 128 + ((64 + acol) ^ sw);

  const u16* Abase = A + (size_t)m0 * K;

#pragma unroll
  for (int t = 0; t < 2; ++t) {
    const int i4 = t * 512 + tid;
    *(float4*)&wf_lds[i4 * 4] = *(const float4*)&Wf[(size_t)m0 * 16 + i4 * 4];
  }

  f32x4 acc[8][4];
#pragma unroll
  for (int i = 0; i < 8; ++i)
#pragma unroll
    for (int j = 0; j < 4; ++j) acc[i][j] = (f32x4){0.f, 0.f, 0.f, 0.f};

  auto STAGE = [&](int b, int isB, int hf, int kt) {
    u16* Lp = &lds[isB * 32768 + (b * 2 + hf) * 8192];
#pragma unroll
    for (int j = 0; j < 2; ++j) {
      const int q = j * 8192 + tid * 16;
      const int tr = hf * 128 + (q >> 7);
      const int gcol = ((q & 127) ^ (((q >> 7) & 7) << 4)) >> 1;
      const u16* gp = isB
          ? Bm + (size_t)((tr >> 4) * 256 + bx16 + (tr & 15)) * K + kt * 64 + gcol
          : Abase + (size_t)tr * K + kt * 64 + gcol;
      gload16(gp, Lp + ((j * 8192 + wid * 1024) >> 1));
    }
  };
  auto LOAD_AV = [&](bf16x8 (&v)[4][2], int b, int mh) {
    const char* p = (const char*)lds + b * 32768 + (wr * 128 + mh * 64) * 128;
#pragma unroll
    for (int mi = 0; mi < 4; ++mi) {
      v[mi][0] = *(const bf16x8*)(p + mi * 2048 + lo0);
      v[mi][1] = *(const bf16x8*)(p + mi * 2048 + lo1);
    }
  };
  auto LOAD_BV = [&](bf16x8 (&v)[2][2], int b, int nq) {
#pragma unroll
    for (int nj = 0; nj < 2; ++nj) {
      const int rb = wc * 64 + (nq * 2 + nj) * 16;
      const char* p = (const char*)lds + 65536 + b * 32768 + rb * 128;
      v[nj][0] = *(const bf16x8*)(p + lo0);
      v[nj][1] = *(const bf16x8*)(p + lo1);
    }
  };

#define QUAD2(AV, BV0, BV1, MH)                                                \
  do {                                                                         \
    _Pragma("unroll") for (int ks = 0; ks < 2; ++ks) {                         \
      _Pragma("unroll") for (int mi = 0; mi < 4; ++mi) {                       \
        _Pragma("unroll") for (int nj = 0; nj < 2; ++nj) {                     \
          acc[(MH)*4 + mi][nj] = MFMA(AV[mi][ks], BV0[nj][ks], acc[(MH)*4 + mi][nj]); \
          acc[(MH)*4 + mi][2 + nj] = MFMA(AV[mi][ks], BV1[nj][ks], acc[(MH)*4 + mi][2 + nj]); \
        }                                                                      \
      }                                                                        \
    }                                                                          \
  } while (0)

  bf16x8 av[4][2], avh[4][2], bv0[2][2], bv1[2][2];

  STAGE(0, 0, 0, 0); STAGE(0, 0, 1, 0); STAGE(0, 1, 0, 0); STAGE(0, 1, 1, 0);
  STAGE(1, 1, 0, 1); STAGE(1, 0, 0, 1);
  asm volatile("s_waitcnt vmcnt(4)" ::: "memory");
  __builtin_amdgcn_s_barrier();

#pragma unroll 1
  for (int i = 0; i < NITER; ++i) {
    const int ta = 2 * i, tb = ta + 1;
    const bool st = (i + 1 < NITER);
    LOAD_AV(av, 0, 0); LOAD_BV(bv0, 0, 0); LOAD_BV(bv1, 0, 1);
    STAGE(1, 0, 1, tb); STAGE(1, 1, 1, tb);
    PH_BAR();
    QUAD2(av, bv0, bv1, 0);
    PH_END();
    LOAD_AV(avh, 0, 1);
    if (st) { STAGE(0, 1, 0, ta + 2); STAGE(0, 0, 0, ta + 2); }
    PH_BAR();
    QUAD2(avh, bv0, bv1, 1);
    if (st) asm volatile("s_waitcnt vmcnt(4)" ::: "memory");
    else    asm volatile("s_waitcnt vmcnt(0)" ::: "memory");
    PH_END();
    LOAD_AV(av, 1, 0); LOAD_BV(bv0, 1, 0); LOAD_BV(bv1, 1, 1);
    if (st) { STAGE(0, 0, 1, ta + 2); STAGE(0, 1, 1, ta + 2); }
    PH_BAR();
    QUAD2(av, bv0, bv1, 0);
    PH_END();
    LOAD_AV(avh, 1, 1);
    if (st) { STAGE(1, 1, 0, tb + 2); STAGE(1, 0, 0, tb + 2); }
    PH_BAR();
    QUAD2(avh, bv0, bv1, 1);
    if (st) asm volatile("s_waitcnt vmcnt(4)" ::: "memory");
    PH_END();
  }

  __syncthreads();
  float* pbuf = (float*)lds;
#pragma unroll
  for (int MI = 0; MI < 8; ++MI) {
    const int mbase = wr * 128 + MI * 16 + (lane >> 4) * 4;
#pragma unroll
    for (int j = 0; j < 4; ++j) {
      const float4 wf4 = *(const float4*)&wf_lds[(mbase + j) * 16 + wc * 4];
      const float p = wf4.x * acc[MI][0][j] + wf4.y * acc[MI][1][j] +
                      wf4.z * acc[MI][2][j] + wf4.w * acc[MI][3][j];
      pbuf[wc * 4096 + (mbase + j) * 16 + (lane & 15)] = p;
    }
  }
  __syncthreads();
  {
    const int m = tid >> 1, r8 = (tid & 1) * 8;
    float s[8];
#pragma unroll
    for (int r = 0; r < 8; ++r) s[r] = 0.f;
#pragma unroll
    for (int w = 0; w < 4; ++w) {
      const float4 a = *(const float4*)&pbuf[w * 4096 + m * 16 + r8];
      const float4 b = *(const float4*)&pbuf[w * 4096 + m * 16 + r8 + 4];
      s[0] += a.x; s[1] += a.y; s[2] += a.z; s[3] += a.w;
      s[4] += b.x; s[5] += b.y; s[6] += b.z; s[7] += b.w;
    }
    bf16x8 o;
#pragma unroll
    for (int r = 0; r < 8; ++r) o[r] = (short)f2bf(s[r]);
    *(bf16x8*)&Hout[(size_t)(m0 + m) * 256 + bx16 + r8] = o;
  }
}
#undef QUAD2

// ============ GEMM2 (R17 best): R6 structure + slim FOLD (C=vz, f32 weights), no setprio ============
__global__ __launch_bounds__(512, 2) void gemm_fold(
    const u16* __restrict__ A,    // h  [8192][256] bf16
    const u16* __restrict__ Bn,   // Rt [16][1024][256] bf16
    const float* __restrict__ W,  // Wr [8192][16] f32
    float* __restrict__ Out) {    // [8192][1024] f32
  __shared__ u16 ldsB[8][8192];   // 128 KB: 4 pair-buffers of 2 half-tiles
  __shared__ float Wlds[16][132]; // f32 weights, [n][row]

  const int tid = threadIdx.x;
  const int lane = tid & 63;
  const int wid = tid >> 6;
  const int kh = wid >> 2;
  const int wrM = (wid >> 1) & 1;
  const int wcN = wid & 1;

  // L2-aware chunked XCD swizzle: chunk = 2 bx x 16 by
  const int L = blockIdx.y * gridDim.x + blockIdx.x;
  const int ordered = (L & 7) * 64 + (L >> 3);
  const int cid = ordered >> 5, win = ordered & 31;
  const int bx = (cid & 3) * 2 + (win & 1);
  const int by = (cid >> 2) * 16 + (win >> 1);
  const int m0 = by * 128, d0 = bx * 128;

  const int arow = lane & 15;
  const int acol = (lane >> 4) * 16;
  const int sw = (arow & 7) << 4;
  const int lo0 = arow * 128 + (acol ^ sw);
  const int lo1 = arow * 128 + ((64 + acol) ^ sw);

  for (int i = tid; i < 128 * 16; i += 512) {
    const int row = i >> 4, n = i & 15;
    Wlds[n][row] = W[(size_t)(m0 + row) * 16 + n];
  }

  auto ASTAGE = [&](int kt) {
    const u16* G = A + (size_t)m0 * 256;
    u16* Lp = &ldsB[kt][0];
#pragma unroll
    for (int j = 0; j < 2; ++j) {
      const int q = j * 8192 + tid * 16;
      const int grow = q >> 7;
      const int gcol = ((q & 127) ^ (((q >> 7) & 7) << 4)) >> 1;
      gload16(G + (size_t)grow * 256 + kt * 64 + gcol, Lp + ((j * 8192 + wid * 1024) >> 1));
    }
  };
  ASTAGE(0); ASTAGE(1); ASTAGE(2); ASTAGE(3);
  __syncthreads();
  bf16x8 avk[4][4];
#pragma unroll
  for (int c2 = 0; c2 < 2; ++c2) {
#pragma unroll
    for (int mi = 0; mi < 4; ++mi) {
      const char* p = (const char*)&ldsB[kh * 2 + c2][0] + (wrM * 64 + mi * 16) * 128;
      avk[c2 * 2 + 0][mi] = *(const bf16x8*)(p + lo0);
      avk[c2 * 2 + 1][mi] = *(const bf16x8*)(p + lo1);
    }
  }
  __syncthreads();

  auto BSTAGE = [&](int ss) {
    const int n = ss >> 1, h = ss & 1, p = ss & 3;
    const u16* G = Bn + ((size_t)n * 1024 + d0) * 256;
#pragma unroll
    for (int t = 0; t < 2; ++t) {
      u16* Lp = &ldsB[2 * p + t][0];
      const int kt = h + 2 * t;
#pragma unroll
      for (int j = 0; j < 2; ++j) {
        const int q = j * 8192 + tid * 16;
        const int grow = q >> 7;
        const int gcol = ((q & 127) ^ (((q >> 7) & 7) << 4)) >> 1;
        gload16(G + (size_t)grow * 256 + kt * 64 + gcol, Lp + ((j * 8192 + wid * 1024) >> 1));
      }
    }
  };

  f32x4 acc_t[4][4], acc_g[4][4];
#pragma unroll
  for (int mi = 0; mi < 4; ++mi)
#pragma unroll
    for (int nj = 0; nj < 4; ++nj) {
      acc_t[mi][nj] = (f32x4){0.f, 0.f, 0.f, 0.f};
      acc_g[mi][nj] = (f32x4){0.f, 0.f, 0.f, 0.f};
    }
  const f32x4 vz = {0.f, 0.f, 0.f, 0.f};
  bf16x8 bv[4][2];
  const int wrow = wrM * 64 + (lane >> 4) * 4;  // + mi*16 per fragment

  BSTAGE(0); BSTAGE(1); BSTAGE(2);
  asm volatile("s_waitcnt vmcnt(8)" ::: "memory");
  __builtin_amdgcn_s_barrier();

  // first==true (h==0): group's ks=0 MFMA uses C=vz -> acc_g zeroed via C operand
  auto SSTEP = [&](int ss, int h, bool do_stage, int vmsel, bool first) {
    const int p = ss & 3;
    const char* pB = (const char*)&ldsB[2 * p + kh][0];
#pragma unroll
    for (int nj = 0; nj < 4; ++nj) {
      const char* q = pB + (wcN * 64 + nj * 16) * 128;
      bv[nj][0] = *(const bf16x8*)(q + lo0);
      bv[nj][1] = *(const bf16x8*)(q + lo1);
    }
    if (do_stage) BSTAGE(ss + 3);
    PH_BAR();
    if (first) {
#pragma unroll
      for (int mi = 0; mi < 4; ++mi)
#pragma unroll
        for (int nj = 0; nj < 4; ++nj)
          acc_g[mi][nj] = MFMA(avk[0][mi], bv[nj][0], vz);
    } else {
#pragma unroll
      for (int mi = 0; mi < 4; ++mi)
#pragma unroll
        for (int nj = 0; nj < 4; ++nj)
          acc_g[mi][nj] = MFMA(avk[2 * h][mi], bv[nj][0], acc_g[mi][nj]);
    }
#pragma unroll
    for (int mi = 0; mi < 4; ++mi)
#pragma unroll
      for (int nj = 0; nj < 4; ++nj)
        acc_g[mi][nj] = MFMA(avk[2 * h + 1][mi], bv[nj][1], acc_g[mi][nj]);
    if (vmsel == 8)      asm volatile("s_waitcnt vmcnt(8)" ::: "memory");
    else if (vmsel == 4) asm volatile("s_waitcnt vmcnt(4)" ::: "memory");
    else if (vmsel == 0) asm volatile("s_waitcnt vmcnt(0)" ::: "memory");
    PH_END();
  };
  // slim FOLD: 4 LDS float4 reads + 16 vector fma, no zeroing, no cvts
  auto FOLD = [&](int n) {
#pragma unroll
    for (int mi = 0; mi < 4; ++mi) {
      const float4 w = *(const float4*)&Wlds[n][wrow + mi * 16];
      const f32x4 wv = {w.x, w.y, w.z, w.w};
#pragma unroll
      for (int nj = 0; nj < 4; ++nj)
        acc_t[mi][nj] += wv * acc_g[mi][nj];
    }
  };

#pragma unroll 1
  for (int nn = 0; nn < 14; ++nn) {
    SSTEP(nn * 2 + 0, 0, true, 8, true);
    SSTEP(nn * 2 + 1, 1, true, 8, false);
    FOLD(nn);
  }
  SSTEP(28, 0, true, 8, true);
  SSTEP(29, 1, false, 4, false);
  FOLD(14);
  SSTEP(30, 0, false, 0, true);
  SSTEP(31, 1, false, -1, false);
  FOLD(15);

  // ---- epilogue: kh-reduce via LDS f32 regions, direct store ----
  __syncthreads();
  float* red = (float*)&ldsB[0][0];
  const int reg = (wrM * 2 + wcN) * 4096;
  if (kh == 1) {
#pragma unroll
    for (int mi = 0; mi < 4; ++mi)
#pragma unroll
      for (int j = 0; j < 4; ++j) {
        const int r = mi * 16 + (lane >> 4) * 4 + j;
#pragma unroll
        for (int nj = 0; nj < 4; ++nj)
          red[reg + r * 64 + nj * 16 + (lane & 15)] = acc_t[mi][nj][j];
      }
  }
  __syncthreads();
  if (kh == 0) {
#pragma unroll
    for (int mi = 0; mi < 4; ++mi) {
      const int rr = mi * 16 + (lane >> 4) * 4;
#pragma unroll
      for (int j = 0; j < 4; ++j) {
        float* orow = Out + (size_t)(m0 + wrM * 64 + rr + j) * 1024 + d0 + wcN * 64 + (lane & 15);
#pragma unroll
        for (int nj = 0; nj < 4; ++nj)
          orow[nj * 16] = acc_t[mi][nj][j] + red[reg + (rr + j) * 64 + nj * 16 + (lane & 15)];
      }
    }
  }
}

extern "C" void kernel_launch(void* const* d_in, const int* in_sizes, int n_in,
                              void* d_out, int out_size, void* d_ws, size_t ws_size,
                              hipStream_t stream) {
  const float* x  = (const float*)d_in[0];   // [8192][1024]
  const float* F  = (const float*)d_in[1];   // [16][1024][256]
  const float* Rk = (const float*)d_in[2];   // [16][256][1024]
  const float* Wf = (const float*)d_in[3];   // [8192][16]
  const float* Wr = (const float*)d_in[4];   // [8192][16]
  float* out = (float*)d_out;                // [8192][1024]

  char* ws = (char*)d_ws;
  u16* X16 = (u16*)(ws);                 // 16 MB  x bf16 [8192][1024]
  u16* B1  = (u16*)(ws + (16u << 20));   //  8 MB  F^T  [(n,r)=4096][1024]
  u16* Rt  = (u16*)(ws + (24u << 20));   //  8 MB  Rk^T [16][1024][256]
  u16* h16 = (u16*)(ws + (32u << 20));   //  4 MB  h bf16 [8192][256]

  cast_x_kernel<<<2048, 256, 0, stream>>>(x, X16, (M_TOK * 1024) / 4);
  tcast_kernel<<<dim3(8, 32, 16), 256, 0, stream>>>(F, B1, 1024, 256);
  tcast_kernel<<<dim3(32, 8, 16), 256, 0, stream>>>(Rk, Rt, 256, 1024);

  // fused stage 1: h = sum_n wf_n * (x @ F_n)
  gemm_h<<<dim3(16, 32, 1), 512, 0, stream>>>(X16, B1, Wf, h16, 1024);

  // stage 2: out = sum_n wr_n * (h @ Rt[n]), slim fold
  gemm_fold<<<dim3(8, 64, 1), 512, 0, stream>>>(h16, Rt, Wr, out);
}